// Round 1
// baseline (764.626 us; speedup 1.0000x reference)
//
#include <hip/hip_runtime.h>

// ---------------------------------------------------------------------------
// Algebraic collapse: the scan is linear & batch-independent.
//   m_{t+1} = A m_t + beta,  A[(j,e),(i,d)] = gate[i,j]*W[i,j,e,d]
//   out = inp @ Weff^T + beff where Weff = Wpost * S * Wpre,
//   S = (A^10)[block15, block0],  c = (sum_{k<10} A^k beta)[block15]
// Iterate augmented QT [144 x 2048] (transposed: c-rows, k-cols), split-bf16
// (hi+lo) with fp32 MFMA accumulation for precision.
// ---------------------------------------------------------------------------

typedef __bf16 bf16x8 __attribute__((ext_vector_type(8)));
typedef float f32x4 __attribute__((ext_vector_type(4)));

__device__ __forceinline__ unsigned short f2bf(float x) {
  unsigned int u = __float_as_uint(x);
  u += 0x7FFFu + ((u >> 16) & 1u);   // round-to-nearest-even
  return (unsigned short)(u >> 16);
}
__device__ __forceinline__ float bf2f(unsigned short s) {
  return __uint_as_float(((unsigned int)s) << 16);
}
__device__ __forceinline__ bf16x8 ldsload(const unsigned short* p) {
  return __builtin_bit_cast(bf16x8, *(const uint4*)p);
}
__device__ __forceinline__ f32x4 mfma16(bf16x8 a, bf16x8 b, f32x4 c) {
  return __builtin_amdgcn_mfma_f32_16x16x32_bf16(a, b, c, 0, 0, 0);
}

#define ND 2048   // num*dim
#define MP 144    // padded iterate rows (128 propagator cols + 1 bias + pad)

// Build A_hi/A_lo bf16 [2048 x 2048], row-major (n=(j,e), k=(i,d)).
__global__ void build_A(const float* __restrict__ W, const float* __restrict__ life,
                        unsigned short* __restrict__ Ahi, unsigned short* __restrict__ Alo) {
  int tt = blockIdx.x * 256 + threadIdx.x;       // 524288 threads, 8 elems each
  long base = (long)tt * 8;
  int n = (int)(base >> 11), k = (int)(base & 2047);
  int j = n >> 7, e = n & 127, i = k >> 7, d0 = k & 127;
  float gv = life[i * 16 + j];
  float gate = gv > 0.f ? gv : 0.f;
  const float* src = W + ((i * 16 + j) * 16384 + e * 128 + d0);
  float4 a = *(const float4*)src, b4 = *(const float4*)(src + 4);
  float vals[8] = {a.x, a.y, a.z, a.w, b4.x, b4.y, b4.z, b4.w};
  union { unsigned short u[8]; uint4 v; } ph, pl;
#pragma unroll
  for (int x = 0; x < 8; ++x) {
    float v = gate * vals[x];
    unsigned short h = f2bf(v);
    ph.u[x] = h;
    pl.u[x] = f2bf(v - bf2f(h));
  }
  *(uint4*)(Ahi + base) = ph.v;
  *(uint4*)(Alo + base) = pl.v;
}

// beta[n=(j,e)] = sum_i gate[i,j]*b[i,j,e]
__global__ void build_beta(const float* __restrict__ bl, const float* __restrict__ life,
                           float* __restrict__ beta) {
  int n = blockIdx.x * 256 + threadIdx.x;
  if (n >= ND) return;
  int j = n >> 7, e = n & 127;
  float s = 0.f;
#pragma unroll
  for (int i = 0; i < 16; ++i) {
    float gv = life[i * 16 + j];
    float g = gv > 0.f ? gv : 0.f;
    s += g * bl[(i * 16 + j) * 128 + e];
  }
  beta[n] = s;
}

// QT_0[c,n] = (c<128 && n==c) ? 1 : 0   (rows 128..143: bias col + zero pad)
__global__ void init_Q(unsigned short* __restrict__ Qhi, unsigned short* __restrict__ Qlo) {
  int t = blockIdx.x * 256 + threadIdx.x;        // MP*ND = 294912
  int c = t >> 11, n = t & 2047;
  Qhi[t] = (c < 128 && n == c) ? (unsigned short)0x3F80 : (unsigned short)0;
  Qlo[t] = 0;
}

// One step: O[c,n] = sum_k QT[c,k] * A[n,k]  (+ beta[n] on row c==128)
// GEMM M=144 (c), N=2048 (n), K=2048. grid 128 n-tiles of 16; 3 waves/block,
// each wave owns 3 m-tiles. Split bf16: acc += ah*bh + al*bh + ah*bl.
__global__ __launch_bounds__(192) void step_kernel(
    const unsigned short* __restrict__ Ahi, const unsigned short* __restrict__ Alo,
    const unsigned short* __restrict__ Qhi, const unsigned short* __restrict__ Qlo,
    const float* __restrict__ beta,
    unsigned short* __restrict__ Ohi, unsigned short* __restrict__ Olo) {
  __shared__ __align__(16) unsigned short Qs_hi[MP][40];   // +8 pad: 2-way-free banks
  __shared__ __align__(16) unsigned short Qs_lo[MP][40];
  __shared__ __align__(16) unsigned short As_hi[16][40];
  __shared__ __align__(16) unsigned short As_lo[16][40];

  const int t = threadIdx.x;
  const int nb = blockIdx.x;
  const int w = t >> 6, lane = t & 63;
  const int r16 = lane & 15, q = lane >> 4;

  f32x4 acc[3];
  acc[0] = acc[1] = acc[2] = (f32x4){0.f, 0.f, 0.f, 0.f};

  for (int kc = 0; kc < 64; ++kc) {
    const int k0 = kc * 32;
    // stage QT slice [144 x 32] hi+lo: 576 16B-slots per array, 3 per thread
#pragma unroll
    for (int rpt = 0; rpt < 3; ++rpt) {
      int s = t + rpt * 192;
      int row = s >> 2, off = (s & 3) * 8;
      *(uint4*)&Qs_hi[row][off] = *(const uint4*)(Qhi + row * ND + k0 + off);
      *(uint4*)&Qs_lo[row][off] = *(const uint4*)(Qlo + row * ND + k0 + off);
    }
    // stage A slice [16 n x 32 k] hi+lo: 128 slots
    if (t < 128) {
      int arr = t >> 6, s2 = t & 63;
      int row = s2 >> 2, off = (s2 & 3) * 8;
      const unsigned short* src = (arr == 0) ? Ahi : Alo;
      unsigned short* dst = (arr == 0) ? &As_hi[row][off] : &As_lo[row][off];
      *(uint4*)dst = *(const uint4*)(src + (nb * 16 + row) * ND + k0 + off);
    }
    __syncthreads();

    bf16x8 bh = ldsload(&As_hi[r16][q * 8]);
    bf16x8 blv = ldsload(&As_lo[r16][q * 8]);
#pragma unroll
    for (int mt = 0; mt < 3; ++mt) {
      const int mrow = (w * 3 + mt) * 16 + r16;
      bf16x8 ah = ldsload(&Qs_hi[mrow][q * 8]);
      bf16x8 al = ldsload(&Qs_lo[mrow][q * 8]);
      acc[mt] = mfma16(ah, bh, acc[mt]);
      acc[mt] = mfma16(al, bh, acc[mt]);
      acc[mt] = mfma16(ah, blv, acc[mt]);
    }
    __syncthreads();
  }

  const int n = nb * 16 + r16;
#pragma unroll
  for (int mt = 0; mt < 3; ++mt) {
    int mbase = (w * 3 + mt) * 16 + q * 4;
#pragma unroll
    for (int r = 0; r < 4; ++r) {
      int m = mbase + r;
      float v = acc[mt][r];
      if (m == 128) v += beta[n];       // augmented bias column
      unsigned short h = f2bf(v);
      Ohi[m * ND + n] = h;
      Olo[m * ND + n] = f2bf(v - bf2f(h));
    }
  }
}

// S[e,d] = QT_10[d, 1920+e]  (fp32 reconstruct)
__global__ void extract_S(const unsigned short* __restrict__ Qhi,
                          const unsigned short* __restrict__ Qlo,
                          float* __restrict__ S) {
  int t = blockIdx.x * 256 + threadIdx.x;   // 16384
  int e = t >> 7, d = t & 127;
  int idx = d * ND + 1920 + e;
  S[e * 128 + d] = bf2f(Qhi[idx]) + bf2f(Qlo[idx]);
}

// g[e] = sum_d S[e,d]*bpre[d] + c[e],  c[e] = QT_10[128, 1920+e]
__global__ void compute_g(const float* __restrict__ S,
                          const unsigned short* __restrict__ Qhi,
                          const unsigned short* __restrict__ Qlo,
                          const float* __restrict__ bpre, float* __restrict__ g) {
  int e = threadIdx.x;   // 128 threads
  int idx = 128 * ND + 1920 + e;
  float s = bf2f(Qhi[idx]) + bf2f(Qlo[idx]);
  for (int d = 0; d < 128; ++d) s += S[e * 128 + d] * bpre[d];
  g[e] = s;
}

// T1[e,ic] = sum_d S[e,d] * Wpre[d,ic]
__global__ void compute_T1(const float* __restrict__ S, const float* __restrict__ Wpre,
                           float* __restrict__ T1) {
  int t = blockIdx.x * 256 + threadIdx.x;   // 65536
  int e = t >> 9, ic = t & 511;
  float s = 0.f;
  for (int d = 0; d < 128; ++d) s += S[e * 128 + d] * Wpre[d * 512 + ic];
  T1[t] = s;
}

// Weff[o,ic] = sum_e Wpost[o,e] * T1[e,ic]  -> store split bf16
__global__ void compute_Weff(const float* __restrict__ Wpost, const float* __restrict__ T1,
                             unsigned short* __restrict__ Whi, unsigned short* __restrict__ Wlo) {
  int t = blockIdx.x * 256 + threadIdx.x;   // 262144
  int o = t >> 9, ic = t & 511;
  float s = 0.f;
  for (int e = 0; e < 128; ++e) s += Wpost[o * 128 + e] * T1[e * 512 + ic];
  unsigned short h = f2bf(s);
  Whi[t] = h;
  Wlo[t] = f2bf(s - bf2f(h));
}

// beff[o] = sum_e Wpost[o,e]*g[e] + bpost[o]
__global__ void compute_beff(const float* __restrict__ Wpost, const float* __restrict__ g,
                             const float* __restrict__ bpost, float* __restrict__ beff) {
  int o = blockIdx.x * 256 + threadIdx.x;
  if (o >= 512) return;
  float s = bpost[o];
  for (int e = 0; e < 128; ++e) s += Wpost[o * 128 + e] * g[e];
  beff[o] = s;
}

// inp -> hi/lo bf16
__global__ void split_inp(const float* __restrict__ inp,
                          unsigned short* __restrict__ hi, unsigned short* __restrict__ lo) {
  long base = ((long)blockIdx.x * 256 + threadIdx.x) * 8;   // 2M elems
  float4 a = *(const float4*)(inp + base), b4 = *(const float4*)(inp + base + 4);
  float vals[8] = {a.x, a.y, a.z, a.w, b4.x, b4.y, b4.z, b4.w};
  union { unsigned short u[8]; uint4 v; } ph, pl;
#pragma unroll
  for (int x = 0; x < 8; ++x) {
    unsigned short h = f2bf(vals[x]);
    ph.u[x] = h;
    pl.u[x] = f2bf(vals[x] - bf2f(h));
  }
  *(uint4*)(hi + base) = ph.v;
  *(uint4*)(lo + base) = pl.v;
}

// out[4096,512] = inp @ Weff^T + beff. M=4096,N=512,K=512, split bf16.
// Block tile 64(M) x 128(N): grid (64,4), 4 waves; wave w owns n-cols [32w,32w+32).
__global__ __launch_bounds__(256) void final_gemm(
    const unsigned short* __restrict__ Ihi, const unsigned short* __restrict__ Ilo,
    const unsigned short* __restrict__ Whi, const unsigned short* __restrict__ Wlo,
    const float* __restrict__ beff, float* __restrict__ out) {
  __shared__ __align__(16) unsigned short Is_hi[64][40], Is_lo[64][40];
  __shared__ __align__(16) unsigned short Ws_hi[128][40], Ws_lo[128][40];
  const int t = threadIdx.x;
  const int mb = blockIdx.x, nb = blockIdx.y;
  const int w = t >> 6, lane = t & 63;
  const int r16 = lane & 15, q = lane >> 4;

  f32x4 acc[4][2];
#pragma unroll
  for (int a = 0; a < 4; ++a)
#pragma unroll
    for (int b = 0; b < 2; ++b) acc[a][b] = (f32x4){0.f, 0.f, 0.f, 0.f};

  for (int kc = 0; kc < 16; ++kc) {
    const int k0 = kc * 32;
#pragma unroll
    for (int rpt = 0; rpt < 6; ++rpt) {
      int slot = t + rpt * 256;
      if (slot < 512) {                       // inp tile [64 x 32] hi+lo
        int arr = slot >> 8, s = slot & 255;
        int row = s >> 2, off = (s & 3) * 8;
        const unsigned short* src = arr ? Ilo : Ihi;
        unsigned short* dst = arr ? &Is_lo[row][off] : &Is_hi[row][off];
        *(uint4*)dst = *(const uint4*)(src + (mb * 64 + row) * 512 + k0 + off);
      } else {                                // Weff tile [128 x 32] hi+lo
        int s = slot - 512;
        int arr = s >> 9, s2 = s & 511;
        int row = s2 >> 2, off = (s2 & 3) * 8;
        const unsigned short* src = arr ? Wlo : Whi;
        unsigned short* dst = arr ? &Ws_lo[row][off] : &Ws_hi[row][off];
        *(uint4*)dst = *(const uint4*)(src + (nb * 128 + row) * 512 + k0 + off);
      }
    }
    __syncthreads();

    bf16x8 bh0 = ldsload(&Ws_hi[w * 32 + r16][q * 8]);
    bf16x8 bl0 = ldsload(&Ws_lo[w * 32 + r16][q * 8]);
    bf16x8 bh1 = ldsload(&Ws_hi[w * 32 + 16 + r16][q * 8]);
    bf16x8 bl1 = ldsload(&Ws_lo[w * 32 + 16 + r16][q * 8]);
#pragma unroll
    for (int mt = 0; mt < 4; ++mt) {
      bf16x8 ah = ldsload(&Is_hi[mt * 16 + r16][q * 8]);
      bf16x8 al = ldsload(&Is_lo[mt * 16 + r16][q * 8]);
      acc[mt][0] = mfma16(ah, bh0, acc[mt][0]);
      acc[mt][0] = mfma16(al, bh0, acc[mt][0]);
      acc[mt][0] = mfma16(ah, bl0, acc[mt][0]);
      acc[mt][1] = mfma16(ah, bh1, acc[mt][1]);
      acc[mt][1] = mfma16(al, bh1, acc[mt][1]);
      acc[mt][1] = mfma16(ah, bl1, acc[mt][1]);
    }
    __syncthreads();
  }

#pragma unroll
  for (int mt = 0; mt < 4; ++mt)
#pragma unroll
    for (int nt = 0; nt < 2; ++nt) {
      int n = nb * 128 + w * 32 + nt * 16 + r16;
      float bv = beff[n];
#pragma unroll
      for (int r = 0; r < 4; ++r) {
        int m = mb * 64 + mt * 16 + q * 4 + r;
        out[m * 512 + n] = acc[mt][nt][r] + bv;
      }
    }
}

extern "C" void kernel_launch(void* const* d_in, const int* in_sizes, int n_in,
                              void* d_out, int out_size, void* d_ws, size_t ws_size,
                              hipStream_t stream) {
  const float* inp   = (const float*)d_in[0];
  const float* Wpre  = (const float*)d_in[1];
  const float* bpre  = (const float*)d_in[2];
  const float* W     = (const float*)d_in[3];
  const float* bl    = (const float*)d_in[4];
  const float* life  = (const float*)d_in[5];
  const float* Wpost = (const float*)d_in[6];
  const float* bpost = (const float*)d_in[7];
  float* out = (float*)d_out;

  char* p = (char*)d_ws;
  auto alloc = [&](size_t bytes) {
    char* r = p;
    p += (bytes + 255) & ~(size_t)255;
    return r;
  };
  unsigned short* Ahi  = (unsigned short*)alloc((size_t)ND * ND * 2);
  unsigned short* Alo  = (unsigned short*)alloc((size_t)ND * ND * 2);
  unsigned short* Q0hi = (unsigned short*)alloc((size_t)MP * ND * 2);
  unsigned short* Q0lo = (unsigned short*)alloc((size_t)MP * ND * 2);
  unsigned short* Q1hi = (unsigned short*)alloc((size_t)MP * ND * 2);
  unsigned short* Q1lo = (unsigned short*)alloc((size_t)MP * ND * 2);
  float* beta = (float*)alloc(ND * 4);
  float* S    = (float*)alloc(128 * 128 * 4);
  float* g    = (float*)alloc(128 * 4);
  float* T1   = (float*)alloc(128 * 512 * 4);
  unsigned short* Whi = (unsigned short*)alloc(512 * 512 * 2);
  unsigned short* Wlo = (unsigned short*)alloc(512 * 512 * 2);
  float* beff = (float*)alloc(512 * 4);
  unsigned short* Ihi = (unsigned short*)alloc((size_t)4096 * 512 * 2);
  unsigned short* Ilo = (unsigned short*)alloc((size_t)4096 * 512 * 2);

  build_A<<<2048, 256, 0, stream>>>(W, life, Ahi, Alo);
  build_beta<<<8, 256, 0, stream>>>(bl, life, beta);
  init_Q<<<1152, 256, 0, stream>>>(Q0hi, Q0lo);
  split_inp<<<1024, 256, 0, stream>>>(inp, Ihi, Ilo);   // independent; early

  for (int s = 0; s < 10; ++s) {
    const unsigned short* qh = (s & 1) ? Q1hi : Q0hi;
    const unsigned short* ql = (s & 1) ? Q1lo : Q0lo;
    unsigned short* oh = (s & 1) ? Q0hi : Q1hi;
    unsigned short* ol = (s & 1) ? Q0lo : Q1lo;
    step_kernel<<<128, 192, 0, stream>>>(Ahi, Alo, qh, ql, beta, oh, ol);
  }
  // 10 steps: final iterate lands in Q0

  extract_S<<<64, 256, 0, stream>>>(Q0hi, Q0lo, S);
  compute_g<<<1, 128, 0, stream>>>(S, Q0hi, Q0lo, bpre, g);
  compute_T1<<<256, 256, 0, stream>>>(S, Wpre, T1);
  compute_Weff<<<1024, 256, 0, stream>>>(Wpost, T1, Whi, Wlo);
  compute_beff<<<2, 256, 0, stream>>>(Wpost, g, bpost, beff);

  final_gemm<<<dim3(64, 4), 256, 0, stream>>>(Ihi, Ilo, Whi, Wlo, beff, out);
}

// Round 2
// 330.841 us; speedup vs baseline: 2.3112x; 2.3112x over previous
//
#include <hip/hip_runtime.h>

// ---------------------------------------------------------------------------
// Algebraic collapse: the scan is linear & batch-independent.
//   m_{t+1} = A m_t + beta,  A[(j,e),(i,d)] = gate[i,j]*W[i,j,e,d]
//   out = inp @ Weff^T + beff,  Weff = Wpost * S * Wpre,
//   S = (A^10)[block15, block0],  c = (sum_{k<10} A^k beta)[block15]
// Iterate QT [144 x 2048] (c-rows, k-cols) in split-bf16 (hi+lo), fp32 MFMA.
// Round 2: barrier-free LDS-free step GEMM (direct global->frag loads),
// split-K=4 with fp32 partials + reduce; step1 = exact transpose of A cols;
// step10 restricted to n in [1920,2048) (only block 15 is ever read).
// ---------------------------------------------------------------------------

typedef __bf16 bf16x8 __attribute__((ext_vector_type(8)));
typedef float f32x4 __attribute__((ext_vector_type(4)));

__device__ __forceinline__ unsigned short f2bf(float x) {
  unsigned int u = __float_as_uint(x);
  u += 0x7FFFu + ((u >> 16) & 1u);   // round-to-nearest-even
  return (unsigned short)(u >> 16);
}
__device__ __forceinline__ float bf2f(unsigned short s) {
  return __uint_as_float(((unsigned int)s) << 16);
}
__device__ __forceinline__ bf16x8 ldg8(const unsigned short* p) {
  return __builtin_bit_cast(bf16x8, *(const uint4*)p);
}
__device__ __forceinline__ f32x4 mfma16(bf16x8 a, bf16x8 b, f32x4 c) {
  return __builtin_amdgcn_mfma_f32_16x16x32_bf16(a, b, c, 0, 0, 0);
}

#define ND 2048   // num*dim
#define MT 144    // padded iterate rows (129 used: 128 propagator + 1 bias)
#define KS 4      // split-K chunks

// Build A_hi/A_lo bf16 [2048 x 2048], row-major (n=(j,e), k=(i,d)).
__global__ void build_A(const float* __restrict__ W, const float* __restrict__ life,
                        unsigned short* __restrict__ Ahi, unsigned short* __restrict__ Alo) {
  int tt = blockIdx.x * 256 + threadIdx.x;       // 524288 threads, 8 elems each
  long base = (long)tt * 8;
  int n = (int)(base >> 11), k = (int)(base & 2047);
  int j = n >> 7, e = n & 127, i = k >> 7, d0 = k & 127;
  float gv = life[i * 16 + j];
  float gate = gv > 0.f ? gv : 0.f;
  const float* src = W + ((i * 16 + j) * 16384 + e * 128 + d0);
  float4 a = *(const float4*)src, b4 = *(const float4*)(src + 4);
  float vals[8] = {a.x, a.y, a.z, a.w, b4.x, b4.y, b4.z, b4.w};
  union { unsigned short u[8]; uint4 v; } ph, pl;
#pragma unroll
  for (int x = 0; x < 8; ++x) {
    float v = gate * vals[x];
    unsigned short h = f2bf(v);
    ph.u[x] = h;
    pl.u[x] = f2bf(v - bf2f(h));
  }
  *(uint4*)(Ahi + base) = ph.v;
  *(uint4*)(Alo + base) = pl.v;
}

// beta[n=(j,e)] = sum_i gate[i,j]*b[i,j,e]
__global__ void build_beta(const float* __restrict__ bl, const float* __restrict__ life,
                           float* __restrict__ beta) {
  int n = blockIdx.x * 256 + threadIdx.x;
  if (n >= ND) return;
  int j = n >> 7, e = n & 127;
  float s = 0.f;
#pragma unroll
  for (int i = 0; i < 16; ++i) {
    float gv = life[i * 16 + j];
    float g = gv > 0.f ? gv : 0.f;
    s += g * bl[(i * 16 + j) * 128 + e];
  }
  beta[n] = s;
}

// Q1[c][n] = A[n][c] for c<128 (exact: step 1 is A * E0); row 128 = beta;
// rows 129..143 = 0. 64 blocks x 256 threads; 32x32 LDS tile transpose.
__global__ __launch_bounds__(256) void init_Q1(
    const unsigned short* __restrict__ Ahi, const unsigned short* __restrict__ Alo,
    const float* __restrict__ beta,
    unsigned short* __restrict__ Qhi, unsigned short* __restrict__ Qlo) {
  __shared__ unsigned short Th[32][36], Tl[32][36];
  const int t = threadIdx.x;
  const int nb = blockIdx.x;           // n-range [nb*32, nb*32+32)
  const int r = t >> 3;                // 0..31
  const int c4 = (t & 7) * 4;          // 0,4,...,28
  for (int cb = 0; cb < 4; ++cb) {     // c-range [cb*32, cb*32+32)
    union { uint2 d; unsigned short u[4]; } vh, vl;
    vh.d = *(const uint2*)(Ahi + (nb * 32 + r) * ND + cb * 32 + c4);
    vl.d = *(const uint2*)(Alo + (nb * 32 + r) * ND + cb * 32 + c4);
#pragma unroll
    for (int i = 0; i < 4; ++i) { Th[r][c4 + i] = vh.u[i]; Tl[r][c4 + i] = vl.u[i]; }
    __syncthreads();
    union { uint2 d; unsigned short u[4]; } oh, ol;
#pragma unroll
    for (int i = 0; i < 4; ++i) { oh.u[i] = Th[c4 + i][r]; ol.u[i] = Tl[c4 + i][r]; }
    *(uint2*)(Qhi + (cb * 32 + r) * ND + nb * 32 + c4) = oh.d;
    *(uint2*)(Qlo + (cb * 32 + r) * ND + nb * 32 + c4) = ol.d;
    __syncthreads();
  }
#pragma unroll
  for (int rep = 0; rep < 2; ++rep) {
    int idx = rep * 256 + t;           // 0..511 -> 16 rows x 32 n
    int rr = idx >> 5, nn = idx & 31;
    int m = 128 + rr, n = nb * 32 + nn;
    unsigned short hh = 0, ll = 0;
    if (rr == 0) { float v = beta[n]; hh = f2bf(v); ll = f2bf(v - bf2f(hh)); }
    Qhi[m * ND + n] = hh;
    Qlo[m * ND + n] = ll;
  }
}

// One step, barrier-free: P[kc][c][n] = sum_{k in chunk} QT[c,k]*A[n,k].
// Grid (nb, kc): nb over 32-wide n-tiles, kc over 4 k-chunks of 512.
// Block = 3 waves; wave g owns m-rows [g*48, g*48+48) (3 m-tiles x 2 n-tiles).
// All MFMA fragments loaded directly from global (row-major-over-K), no LDS.
__global__ __launch_bounds__(192) void step_kernel(
    const unsigned short* __restrict__ Ahi, const unsigned short* __restrict__ Alo,
    const unsigned short* __restrict__ Qhi, const unsigned short* __restrict__ Qlo,
    float* __restrict__ P, int nb_off) {
  const int t = threadIdx.x;
  const int g = t >> 6, lane = t & 63;
  const int r16 = lane & 15, q = lane >> 4;
  const int nb = blockIdx.x + nb_off;
  const int kc = blockIdx.y;
  const int kbase = kc * 512 + q * 8;
  const int n0 = nb * 32;

  const unsigned short* pB0h = Ahi + (n0 + r16) * ND + kbase;      // A rows (B-op)
  const unsigned short* pB0l = Alo + (n0 + r16) * ND + kbase;
  const unsigned short* pB1h = pB0h + 16 * ND;
  const unsigned short* pB1l = pB0l + 16 * ND;
  const int m0 = g * 48 + r16;
  const unsigned short* pA0h = Qhi + m0 * ND + kbase;              // Q rows (A-op)
  const unsigned short* pA0l = Qlo + m0 * ND + kbase;

  f32x4 acc[3][2];
#pragma unroll
  for (int mt = 0; mt < 3; ++mt)
#pragma unroll
    for (int nt = 0; nt < 2; ++nt) acc[mt][nt] = (f32x4){0.f, 0.f, 0.f, 0.f};

#pragma unroll 2
  for (int it = 0; it < 16; ++it) {
    const int ko = it * 32;
    bf16x8 b0h = ldg8(pB0h + ko), b0l = ldg8(pB0l + ko);
    bf16x8 b1h = ldg8(pB1h + ko), b1l = ldg8(pB1l + ko);
    bf16x8 a0h = ldg8(pA0h + ko), a0l = ldg8(pA0l + ko);
    bf16x8 a1h = ldg8(pA0h + 16 * ND + ko), a1l = ldg8(pA0l + 16 * ND + ko);
    bf16x8 a2h = ldg8(pA0h + 32 * ND + ko), a2l = ldg8(pA0l + 32 * ND + ko);

    acc[0][0] = mfma16(a0h, b0h, acc[0][0]);
    acc[0][0] = mfma16(a0l, b0h, acc[0][0]);
    acc[0][0] = mfma16(a0h, b0l, acc[0][0]);
    acc[1][0] = mfma16(a1h, b0h, acc[1][0]);
    acc[1][0] = mfma16(a1l, b0h, acc[1][0]);
    acc[1][0] = mfma16(a1h, b0l, acc[1][0]);
    acc[2][0] = mfma16(a2h, b0h, acc[2][0]);
    acc[2][0] = mfma16(a2l, b0h, acc[2][0]);
    acc[2][0] = mfma16(a2h, b0l, acc[2][0]);
    acc[0][1] = mfma16(a0h, b1h, acc[0][1]);
    acc[0][1] = mfma16(a0l, b1h, acc[0][1]);
    acc[0][1] = mfma16(a0h, b1l, acc[0][1]);
    acc[1][1] = mfma16(a1h, b1h, acc[1][1]);
    acc[1][1] = mfma16(a1l, b1h, acc[1][1]);
    acc[1][1] = mfma16(a1h, b1l, acc[1][1]);
    acc[2][1] = mfma16(a2h, b1h, acc[2][1]);
    acc[2][1] = mfma16(a2l, b1h, acc[2][1]);
    acc[2][1] = mfma16(a2h, b1l, acc[2][1]);
  }

  float* Pk = P + kc * (MT * ND);
#pragma unroll
  for (int mt = 0; mt < 3; ++mt)
#pragma unroll
    for (int nt = 0; nt < 2; ++nt) {
      int mbase = g * 48 + mt * 16 + q * 4;
      int n = n0 + nt * 16 + r16;
#pragma unroll
      for (int r = 0; r < 4; ++r)
        Pk[(mbase + r) * ND + n] = acc[mt][nt][r];
    }
}

// Sum KS partials, add beta on row 128, write split bf16. nw cols from n_off.
__global__ void reduce_step(const float* __restrict__ P, const float* __restrict__ beta,
                            unsigned short* __restrict__ Ohi, unsigned short* __restrict__ Olo,
                            int n_off, int nw) {
  int t = blockIdx.x * 256 + threadIdx.x;   // MT*nw/4 threads
  int per_row = nw >> 2;
  int m = t / per_row;
  if (m >= MT) return;
  int n = n_off + (t - m * per_row) * 4;
  int idx = m * ND + n;
  const int stride = MT * ND;
  float4 s0 = *(const float4*)(P + idx);
  float4 s1 = *(const float4*)(P + stride + idx);
  float4 s2 = *(const float4*)(P + 2 * stride + idx);
  float4 s3 = *(const float4*)(P + 3 * stride + idx);
  float v0 = s0.x + s1.x + s2.x + s3.x;
  float v1 = s0.y + s1.y + s2.y + s3.y;
  float v2 = s0.z + s1.z + s2.z + s3.z;
  float v3 = s0.w + s1.w + s2.w + s3.w;
  if (m == 128) {
    float4 b4 = *(const float4*)(beta + n);
    v0 += b4.x; v1 += b4.y; v2 += b4.z; v3 += b4.w;
  }
  union { unsigned short u[4]; uint2 d; } h, l;
  float vv[4] = {v0, v1, v2, v3};
#pragma unroll
  for (int i = 0; i < 4; ++i) {
    unsigned short hh = f2bf(vv[i]);
    h.u[i] = hh;
    l.u[i] = f2bf(vv[i] - bf2f(hh));
  }
  *(uint2*)(Ohi + idx) = h.d;
  *(uint2*)(Olo + idx) = l.d;
}

// S[e,d] = QT_10[d, 1920+e]  (fp32 reconstruct)
__global__ void extract_S(const unsigned short* __restrict__ Qhi,
                          const unsigned short* __restrict__ Qlo,
                          float* __restrict__ S) {
  int t = blockIdx.x * 256 + threadIdx.x;   // 16384
  int e = t >> 7, d = t & 127;
  int idx = d * ND + 1920 + e;
  S[e * 128 + d] = bf2f(Qhi[idx]) + bf2f(Qlo[idx]);
}

// g[e] = sum_d S[e,d]*bpre[d] + c[e],  c[e] = QT_10[128, 1920+e]
__global__ void compute_g(const float* __restrict__ S,
                          const unsigned short* __restrict__ Qhi,
                          const unsigned short* __restrict__ Qlo,
                          const float* __restrict__ bpre, float* __restrict__ g) {
  int e = threadIdx.x;   // 128 threads
  int idx = 128 * ND + 1920 + e;
  float s = bf2f(Qhi[idx]) + bf2f(Qlo[idx]);
  for (int d = 0; d < 128; ++d) s += S[e * 128 + d] * bpre[d];
  g[e] = s;
}

// T1[e,ic] = sum_d S[e,d] * Wpre[d,ic]
__global__ void compute_T1(const float* __restrict__ S, const float* __restrict__ Wpre,
                           float* __restrict__ T1) {
  int t = blockIdx.x * 256 + threadIdx.x;   // 65536
  int e = t >> 9, ic = t & 511;
  float s = 0.f;
  for (int d = 0; d < 128; ++d) s += S[e * 128 + d] * Wpre[d * 512 + ic];
  T1[t] = s;
}

// Weff[o,ic] = sum_e Wpost[o,e] * T1[e,ic]  -> store split bf16
__global__ void compute_Weff(const float* __restrict__ Wpost, const float* __restrict__ T1,
                             unsigned short* __restrict__ Whi, unsigned short* __restrict__ Wlo) {
  int t = blockIdx.x * 256 + threadIdx.x;   // 262144
  int o = t >> 9, ic = t & 511;
  float s = 0.f;
  for (int e = 0; e < 128; ++e) s += Wpost[o * 128 + e] * T1[e * 512 + ic];
  unsigned short h = f2bf(s);
  Whi[t] = h;
  Wlo[t] = f2bf(s - bf2f(h));
}

// beff[o] = sum_e Wpost[o,e]*g[e] + bpost[o]
__global__ void compute_beff(const float* __restrict__ Wpost, const float* __restrict__ g,
                             const float* __restrict__ bpost, float* __restrict__ beff) {
  int o = blockIdx.x * 256 + threadIdx.x;
  if (o >= 512) return;
  float s = bpost[o];
  for (int e = 0; e < 128; ++e) s += Wpost[o * 128 + e] * g[e];
  beff[o] = s;
}

// inp -> hi/lo bf16
__global__ void split_inp(const float* __restrict__ inp,
                          unsigned short* __restrict__ hi, unsigned short* __restrict__ lo) {
  long base = ((long)blockIdx.x * 256 + threadIdx.x) * 8;   // 2M elems
  float4 a = *(const float4*)(inp + base), b4 = *(const float4*)(inp + base + 4);
  float vals[8] = {a.x, a.y, a.z, a.w, b4.x, b4.y, b4.z, b4.w};
  union { unsigned short u[8]; uint4 v; } ph, pl;
#pragma unroll
  for (int x = 0; x < 8; ++x) {
    unsigned short h = f2bf(vals[x]);
    ph.u[x] = h;
    pl.u[x] = f2bf(vals[x] - bf2f(h));
  }
  *(uint4*)(hi + base) = ph.v;
  *(uint4*)(lo + base) = pl.v;
}

// out[4096,512] = inp @ Weff^T + beff. M=4096,N=512,K=512, split bf16.
// Block tile 64(M) x 128(N): grid (64,4), 4 waves; wave w owns n-cols [32w,32w+32).
__global__ __launch_bounds__(256) void final_gemm(
    const unsigned short* __restrict__ Ihi, const unsigned short* __restrict__ Ilo,
    const unsigned short* __restrict__ Whi, const unsigned short* __restrict__ Wlo,
    const float* __restrict__ beff, float* __restrict__ out) {
  __shared__ __align__(16) unsigned short Is_hi[64][40], Is_lo[64][40];
  __shared__ __align__(16) unsigned short Ws_hi[128][40], Ws_lo[128][40];
  const int t = threadIdx.x;
  const int mb = blockIdx.x, nb = blockIdx.y;
  const int w = t >> 6, lane = t & 63;
  const int r16 = lane & 15, q = lane >> 4;

  f32x4 acc[4][2];
#pragma unroll
  for (int a = 0; a < 4; ++a)
#pragma unroll
    for (int b = 0; b < 2; ++b) acc[a][b] = (f32x4){0.f, 0.f, 0.f, 0.f};

  for (int kc = 0; kc < 16; ++kc) {
    const int k0 = kc * 32;
#pragma unroll
    for (int rpt = 0; rpt < 6; ++rpt) {
      int slot = t + rpt * 256;
      if (slot < 512) {
        int arr = slot >> 8, s = slot & 255;
        int row = s >> 2, off = (s & 3) * 8;
        const unsigned short* src = arr ? Ilo : Ihi;
        unsigned short* dst = arr ? &Is_lo[row][off] : &Is_hi[row][off];
        *(uint4*)dst = *(const uint4*)(src + (mb * 64 + row) * 512 + k0 + off);
      } else {
        int s = slot - 512;
        int arr = s >> 9, s2 = s & 511;
        int row = s2 >> 2, off = (s2 & 3) * 8;
        const unsigned short* src = arr ? Wlo : Whi;
        unsigned short* dst = arr ? &Ws_lo[row][off] : &Ws_hi[row][off];
        *(uint4*)dst = *(const uint4*)(src + (nb * 128 + row) * 512 + k0 + off);
      }
    }
    __syncthreads();

    bf16x8 bh0 = __builtin_bit_cast(bf16x8, *(const uint4*)&Ws_hi[w * 32 + r16][q * 8]);
    bf16x8 bl0 = __builtin_bit_cast(bf16x8, *(const uint4*)&Ws_lo[w * 32 + r16][q * 8]);
    bf16x8 bh1 = __builtin_bit_cast(bf16x8, *(const uint4*)&Ws_hi[w * 32 + 16 + r16][q * 8]);
    bf16x8 bl1 = __builtin_bit_cast(bf16x8, *(const uint4*)&Ws_lo[w * 32 + 16 + r16][q * 8]);
#pragma unroll
    for (int mt = 0; mt < 4; ++mt) {
      bf16x8 ah = __builtin_bit_cast(bf16x8, *(const uint4*)&Is_hi[mt * 16 + r16][q * 8]);
      bf16x8 al = __builtin_bit_cast(bf16x8, *(const uint4*)&Is_lo[mt * 16 + r16][q * 8]);
      acc[mt][0] = mfma16(ah, bh0, acc[mt][0]);
      acc[mt][0] = mfma16(al, bh0, acc[mt][0]);
      acc[mt][0] = mfma16(ah, bl0, acc[mt][0]);
      acc[mt][1] = mfma16(ah, bh1, acc[mt][1]);
      acc[mt][1] = mfma16(al, bh1, acc[mt][1]);
      acc[mt][1] = mfma16(ah, bl1, acc[mt][1]);
    }
    __syncthreads();
  }

#pragma unroll
  for (int mt = 0; mt < 4; ++mt)
#pragma unroll
    for (int nt = 0; nt < 2; ++nt) {
      int n = nb * 128 + w * 32 + nt * 16 + r16;
      float bv = beff[n];
#pragma unroll
      for (int r = 0; r < 4; ++r) {
        int m = mb * 64 + mt * 16 + q * 4 + r;
        out[m * 512 + n] = acc[mt][nt][r] + bv;
      }
    }
}

extern "C" void kernel_launch(void* const* d_in, const int* in_sizes, int n_in,
                              void* d_out, int out_size, void* d_ws, size_t ws_size,
                              hipStream_t stream) {
  const float* inp   = (const float*)d_in[0];
  const float* Wpre  = (const float*)d_in[1];
  const float* bpre  = (const float*)d_in[2];
  const float* W     = (const float*)d_in[3];
  const float* bl    = (const float*)d_in[4];
  const float* life  = (const float*)d_in[5];
  const float* Wpost = (const float*)d_in[6];
  const float* bpost = (const float*)d_in[7];
  float* out = (float*)d_out;

  char* p = (char*)d_ws;
  auto alloc = [&](size_t bytes) {
    char* r = p;
    p += (bytes + 255) & ~(size_t)255;
    return r;
  };
  unsigned short* Ahi  = (unsigned short*)alloc((size_t)ND * ND * 2);
  unsigned short* Alo  = (unsigned short*)alloc((size_t)ND * ND * 2);
  unsigned short* QAhi = (unsigned short*)alloc((size_t)MT * ND * 2);
  unsigned short* QAlo = (unsigned short*)alloc((size_t)MT * ND * 2);
  unsigned short* QBhi = (unsigned short*)alloc((size_t)MT * ND * 2);
  unsigned short* QBlo = (unsigned short*)alloc((size_t)MT * ND * 2);
  float* beta = (float*)alloc(ND * 4);
  float* S    = (float*)alloc(128 * 128 * 4);
  float* g    = (float*)alloc(128 * 4);
  float* T1   = (float*)alloc(128 * 512 * 4);
  unsigned short* Whi = (unsigned short*)alloc(512 * 512 * 2);
  unsigned short* Wlo = (unsigned short*)alloc(512 * 512 * 2);
  float* beff = (float*)alloc(512 * 4);
  unsigned short* Ihi = (unsigned short*)alloc((size_t)4096 * 512 * 2);
  unsigned short* Ilo = (unsigned short*)alloc((size_t)4096 * 512 * 2);
  // P (split-K partials, KS*MT*ND fp32 = 4.72 MB) aliases Ihi/Ilo (8.39 MB):
  // P is live only during the step loop; Ihi/Ilo are written by split_inp after.
  float* P = (float*)Ihi;

  build_A<<<2048, 256, 0, stream>>>(W, life, Ahi, Alo);
  build_beta<<<8, 256, 0, stream>>>(bl, life, beta);
  init_Q1<<<64, 256, 0, stream>>>(Ahi, Alo, beta, QAhi, QAlo);   // t=1 exact

  // steps t=2..10: 8 full + 1 restricted to n in [1920,2048)
  const unsigned short *qh = QAhi, *ql = QAlo;
  unsigned short *oh = QBhi, *ol = QBlo;
  for (int i = 1; i <= 9; ++i) {
    if (i < 9) {
      step_kernel<<<dim3(64, KS), 192, 0, stream>>>(Ahi, Alo, qh, ql, P, 0);
      reduce_step<<<288, 256, 0, stream>>>(P, beta, oh, ol, 0, 2048);
    } else {
      step_kernel<<<dim3(4, KS), 192, 0, stream>>>(Ahi, Alo, qh, ql, P, 60);
      reduce_step<<<18, 256, 0, stream>>>(P, beta, oh, ol, 1920, 128);
    }
    const unsigned short* th = qh; qh = oh; oh = (unsigned short*)th;
    const unsigned short* tl = ql; ql = ol; ol = (unsigned short*)tl;
  }
  // after 9 launches the final iterate is in (qh, ql) = QB

  split_inp<<<1024, 256, 0, stream>>>(inp, Ihi, Ilo);            // after P dies
  extract_S<<<64, 256, 0, stream>>>(qh, ql, S);
  compute_g<<<1, 128, 0, stream>>>(S, qh, ql, bpre, g);
  compute_T1<<<256, 256, 0, stream>>>(S, Wpre, T1);
  compute_Weff<<<1024, 256, 0, stream>>>(Wpost, T1, Whi, Wlo);
  compute_beff<<<2, 256, 0, stream>>>(Wpost, g, bpost, beff);

  final_gemm<<<dim3(64, 4), 256, 0, stream>>>(Ihi, Ilo, Whi, Wlo, beff, out);
}